// Round 3
// baseline (138.536 us; speedup 1.0000x reference)
//
#include <hip/hip_runtime.h>
#include <math.h>

typedef __attribute__((ext_vector_type(8))) _Float16 f16x8;
typedef __attribute__((ext_vector_type(4))) float f32x4;

#define BT 8192     // T rows per batch
#define BS 200      // S cols per batch
#define SP 208      // S padded to multiple of 16
#define DD 256      // D
#define TM 128      // T rows per block (4 waves x 32)
#define LSTR 40     // LDS row stride in halves (32 + 8 pad -> 2-way max bank alias)
#define NJ 13       // S tiles of 16 (13*16 = 208)

__global__ __launch_bounds__(256, 2)
void cos_scorer_kernel(const float* __restrict__ X, const float* __restrict__ SPK,
                       float* __restrict__ OUT) {
    const int b   = blockIdx.y;
    const int t0  = blockIdx.x * TM;
    const int tid = threadIdx.x;
    const int wid = tid >> 6;
    const int lane = tid & 63;
    const int lr  = lane & 15;   // fragment row (A) / col (B)
    const int lg  = lane >> 4;   // k-group

    __shared__ _Float16 Shi[SP * LSTR];
    __shared__ _Float16 Slo[SP * LSTR];
    __shared__ float sn_l[SP];

    const float* __restrict__ spk_b = SPK + (size_t)b * BS * DD;

    // A-row base pointers for this wave's two 16-row tiles
    const float* __restrict__ xrow0 = X + ((size_t)b * BT + t0 + wid * 32 + lr) * DD;
    const float* __restrict__ xrow1 = xrow0 + 16 * DD;

    // preload A f32 for kb = 0 (8 floats per row-tile per lane)
    float4 pa00 = *(const float4*)(xrow0 + lg * 8);
    float4 pa01 = *(const float4*)(xrow0 + lg * 8 + 4);
    float4 pa10 = *(const float4*)(xrow1 + lg * 8);
    float4 pa11 = *(const float4*)(xrow1 + lg * 8 + 4);

    // spk norms: one thread per (padded) spk row; spk is tiny & L2-hot
    if (tid < SP) {
        float ss = 0.f;
        if (tid < BS) {
            const float4* p = (const float4*)(spk_b + tid * DD);
            #pragma unroll 8
            for (int i = 0; i < DD / 4; ++i) {
                float4 v = p[i];
                ss = fmaf(v.x, v.x, ss); ss = fmaf(v.y, v.y, ss);
                ss = fmaf(v.z, v.z, ss); ss = fmaf(v.w, v.w, ss);
            }
        }
        sn_l[tid] = sqrtf(ss);
    }

    f32x4 acc[2][NJ];
    #pragma unroll
    for (int rt = 0; rt < 2; ++rt)
        #pragma unroll
        for (int j = 0; j < NJ; ++j)
            acc[rt][j] = (f32x4){0.f, 0.f, 0.f, 0.f};

    float ss0 = 0.f, ss1 = 0.f;  // per-lane partial sum-of-squares for A rows

    for (int kb = 0; kb < 8; ++kb) {
        // ---- stage spk k-chunk into LDS as f16 hi/lo (converted inline) ----
        for (int i = tid; i < SP * 4; i += 256) {
            int s = i >> 2, part = i & 3;
            f16x8 hi, lo;
            #pragma unroll
            for (int e = 0; e < 8; ++e) { hi[e] = (_Float16)0.f; lo[e] = (_Float16)0.f; }
            if (s < BS) {
                const float* src = spk_b + s * DD + kb * 32 + part * 8;
                float4 v0 = *(const float4*)src;
                float4 v1 = *(const float4*)(src + 4);
                float xv[8] = {v0.x, v0.y, v0.z, v0.w, v1.x, v1.y, v1.z, v1.w};
                #pragma unroll
                for (int e = 0; e < 8; ++e) {
                    _Float16 h = (_Float16)xv[e];
                    hi[e] = h;
                    lo[e] = (_Float16)(xv[e] - (float)h);
                }
            }
            int off = s * LSTR + part * 8;
            *(f16x8*)&Shi[off] = hi;
            *(f16x8*)&Slo[off] = lo;
        }
        __syncthreads();

        // ---- convert current A regs -> hi/lo fragments, accumulate sumsq ----
        f16x8 ahi0, alo0, ahi1, alo1;
        {
            float xv0[8] = {pa00.x, pa00.y, pa00.z, pa00.w, pa01.x, pa01.y, pa01.z, pa01.w};
            float xv1[8] = {pa10.x, pa10.y, pa10.z, pa10.w, pa11.x, pa11.y, pa11.z, pa11.w};
            #pragma unroll
            for (int e = 0; e < 8; ++e) {
                _Float16 h0 = (_Float16)xv0[e];
                ahi0[e] = h0; alo0[e] = (_Float16)(xv0[e] - (float)h0);
                ss0 = fmaf(xv0[e], xv0[e], ss0);
                _Float16 h1 = (_Float16)xv1[e];
                ahi1[e] = h1; alo1[e] = (_Float16)(xv1[e] - (float)h1);
                ss1 = fmaf(xv1[e], xv1[e], ss1);
            }
        }
        // prefetch next kb's A f32 (overlaps MFMA + next staging)
        if (kb < 7) {
            int o = (kb + 1) * 32 + lg * 8;
            pa00 = *(const float4*)(xrow0 + o);
            pa01 = *(const float4*)(xrow0 + o + 4);
            pa10 = *(const float4*)(xrow1 + o);
            pa11 = *(const float4*)(xrow1 + o + 4);
        }

        // ---- MFMA across all S tiles: hi*hi + lo*hi + hi*lo ----
        #pragma unroll
        for (int j = 0; j < NJ; ++j) {
            int boff = (j * 16 + lr) * LSTR + lg * 8;
            f16x8 bhi = *(const f16x8*)&Shi[boff];
            f16x8 blo = *(const f16x8*)&Slo[boff];
            acc[0][j] = __builtin_amdgcn_mfma_f32_16x16x32_f16(ahi0, bhi, acc[0][j], 0, 0, 0);
            acc[1][j] = __builtin_amdgcn_mfma_f32_16x16x32_f16(ahi1, bhi, acc[1][j], 0, 0, 0);
            acc[0][j] = __builtin_amdgcn_mfma_f32_16x16x32_f16(alo0, bhi, acc[0][j], 0, 0, 0);
            acc[1][j] = __builtin_amdgcn_mfma_f32_16x16x32_f16(alo1, bhi, acc[1][j], 0, 0, 0);
            acc[0][j] = __builtin_amdgcn_mfma_f32_16x16x32_f16(ahi0, blo, acc[0][j], 0, 0, 0);
            acc[1][j] = __builtin_amdgcn_mfma_f32_16x16x32_f16(ahi1, blo, acc[1][j], 0, 0, 0);
        }
        __syncthreads();
    }

    // ---- epilogue: finish X norms, divide, store ----
    ss0 += __shfl_xor(ss0, 16, 64);
    ss0 += __shfl_xor(ss0, 32, 64);
    ss1 += __shfl_xor(ss1, 16, 64);
    ss1 += __shfl_xor(ss1, 32, 64);

    #pragma unroll
    for (int rt = 0; rt < 2; ++rt) {
        float ssv = rt ? ss1 : ss0;
        #pragma unroll
        for (int reg = 0; reg < 4; ++reg) {
            int rc = lg * 4 + reg;                 // C/D row within 16 (m89-verified)
            float xn = sqrtf(__shfl(ssv, rc, 64)); // sumsq lives at lane (row index)
            int row = t0 + wid * 32 + rt * 16 + rc;
            float* orow = OUT + ((size_t)b * BT + row) * BS;
            #pragma unroll
            for (int j = 0; j < NJ; ++j) {
                int col = j * 16 + lr;             // C/D col = lane&15
                if (col < BS) {
                    float denom = fmaxf(xn * sn_l[col], 1e-8f);
                    orow[col] = acc[rt][j][reg] * __builtin_amdgcn_rcpf(denom);
                }
            }
        }
    }
}

extern "C" void kernel_launch(void* const* d_in, const int* in_sizes, int n_in,
                              void* d_out, int out_size, void* d_ws, size_t ws_size,
                              hipStream_t stream) {
    const float* X   = (const float*)d_in[0];   // xs_pad [8, 8192, 256] f32
    const float* SPK = (const float*)d_in[1];   // spk_emb [8, 200, 256] f32
    float* OUT = (float*)d_out;                 // [8, 8192, 200] f32

    dim3 grid(BT / TM, 8);
    dim3 block(256);
    hipLaunchKernelGGL(cos_scorer_kernel, grid, block, 0, stream, X, SPK, OUT);
}